// Round 1
// baseline (519.260 us; speedup 1.0000x reference)
//
#include <hip/hip_runtime.h>
#include <stdint.h>

#define NROWS 8192
#define DIM 64
#define EPS 0.1f

// ---------- helpers ----------

__device__ __forceinline__ float wave_reduce_add(float v) {
  #pragma unroll
  for (int off = 32; off > 0; off >>= 1) v += __shfl_down(v, off, 64);
  return v;
}

// float -> bf16 bits, round-to-nearest-even (inputs here are positive normals)
__device__ __forceinline__ unsigned short f2bf(float f) {
  uint32_t u = __float_as_uint(f);
  uint32_t r = (u + 0x7fffu + ((u >> 16) & 1u)) >> 16;
  return (unsigned short)r;
}

__device__ __forceinline__ float bf2f_lo(uint32_t w) {  // low 16 bits
  return __uint_as_float(w << 16);
}
__device__ __forceinline__ float bf2f_hi(uint32_t w) {  // high 16 bits
  return __uint_as_float(w & 0xffff0000u);
}

// ---------- kernels ----------

// Row squared-norms for P (first 8192 block-waves) and Q (next 8192).
// One wave (64 lanes) per row; DIM==64 so lane l holds element l.
__global__ __launch_bounds__(256) void rownorm_kernel(
    const float* __restrict__ P, const float* __restrict__ Q,
    float* __restrict__ p2, float* __restrict__ q2) {
  int wid  = threadIdx.x >> 6;
  int lane = threadIdx.x & 63;
  int row  = blockIdx.x * 4 + wid;  // 0..16383
  const float* X;
  float* out;
  int r;
  if (row < NROWS) { X = P; out = p2; r = row; }
  else             { X = Q; out = q2; r = row - NROWS; }
  float v = X[(size_t)r * DIM + lane];
  float s = wave_reduce_add(v * v);
  if (lane == 0) out[r] = s;
}

__global__ void init_u_kernel(float* __restrict__ u) {
  int i = blockIdx.x * blockDim.x + threadIdx.x;
  if (i < NROWS) u[i] = 1.0f / 64.0f;   // u0 = ones/D, D = 64
}

// K[i][j] = bf16( exp(-sqrt(max(p2_i + q2_j - 2*P_i.Q_j, 0)) / EPS) )
// 64x64 output tile per block, 256 threads, 4x4 register tile per thread.
// LDS tiles stored transposed: Ps[k][i], row stride 68 floats (16B aligned).
__global__ __launch_bounds__(256) void kgen_kernel(
    const float* __restrict__ P, const float* __restrict__ Q,
    const float* __restrict__ p2, const float* __restrict__ q2,
    unsigned short* __restrict__ K) {
  __shared__ float Ps[64][68];
  __shared__ float Qs[64][68];
  const int t  = threadIdx.x;
  const int bi = blockIdx.y * 64;  // P row base (K rows)
  const int bj = blockIdx.x * 64;  // Q row base (K cols)

  // Load 64x64 fp32 tiles with float4 global reads; write transposed to LDS.
  {
    const float4* P4 = (const float4*)(P + (size_t)bi * DIM);
    const float4* Q4 = (const float4*)(Q + (size_t)bj * DIM);
    #pragma unroll
    for (int s = 0; s < 4; ++s) {
      int idx = t + s * 256;   // 0..1023 ; row = idx>>4, float4-col = idx&15
      int rr = idx >> 4;
      int c4 = (idx & 15) * 4;
      float4 pv = P4[idx];
      float4 qv = Q4[idx];
      Ps[c4 + 0][rr] = pv.x; Ps[c4 + 1][rr] = pv.y;
      Ps[c4 + 2][rr] = pv.z; Ps[c4 + 3][rr] = pv.w;
      Qs[c4 + 0][rr] = qv.x; Qs[c4 + 1][rr] = qv.y;
      Qs[c4 + 2][rr] = qv.z; Qs[c4 + 3][rr] = qv.w;
    }
  }
  __syncthreads();

  const int tx = t & 15;   // -> K cols
  const int ty = t >> 4;   // -> K rows
  float acc[4][4] = {};
  #pragma unroll 8
  for (int k = 0; k < 64; ++k) {
    float4 pv = *(const float4*)&Ps[k][ty * 4];
    float4 qv = *(const float4*)&Qs[k][tx * 4];
    float pa[4] = {pv.x, pv.y, pv.z, pv.w};
    float qa[4] = {qv.x, qv.y, qv.z, qv.w};
    #pragma unroll
    for (int a = 0; a < 4; ++a)
      #pragma unroll
      for (int b = 0; b < 4; ++b)
        acc[a][b] = fmaf(pa[a], qa[b], acc[a][b]);
  }

  float pn[4], qn[4];
  #pragma unroll
  for (int a = 0; a < 4; ++a) pn[a] = p2[bi + ty * 4 + a];
  #pragma unroll
  for (int b = 0; b < 4; ++b) qn[b] = q2[bj + tx * 4 + b];

  #pragma unroll
  for (int a = 0; a < 4; ++a) {
    ushort4 pack;
    unsigned short w[4];
    #pragma unroll
    for (int b = 0; b < 4; ++b) {
      float sq = pn[a] + qn[b] - 2.0f * acc[a][b];
      float c  = sqrtf(fmaxf(sq, 0.0f));
      w[b] = f2bf(__expf(c * (-1.0f / EPS)));
    }
    pack.x = w[0]; pack.y = w[1]; pack.z = w[2]; pack.w = w[3];
    size_t row = (size_t)(bi + ty * 4 + a);
    *(ushort4*)&K[row * NROWS + bj + tx * 4] = pack;
  }
}

// y[i] = 1 / sum_j K[i][j] * x[j]   (one block per row, 16B K loads)
__global__ __launch_bounds__(256) void matvec_kernel(
    const unsigned short* __restrict__ K, const float* __restrict__ x,
    float* __restrict__ y) {
  const int row = blockIdx.x;
  const uint4* krow = (const uint4*)(K + (size_t)row * NROWS);  // 1024 uint4
  const int t = threadIdx.x;
  float acc = 0.f;
  #pragma unroll
  for (int s = 0; s < 4; ++s) {
    int idx = t + s * 256;
    uint4 kw = krow[idx];
    const float4* x4 = (const float4*)(x + idx * 8);
    float4 xa = x4[0];
    float4 xb = x4[1];
    acc += bf2f_lo(kw.x) * xa.x + bf2f_hi(kw.x) * xa.y
         + bf2f_lo(kw.y) * xa.z + bf2f_hi(kw.y) * xa.w
         + bf2f_lo(kw.z) * xb.x + bf2f_hi(kw.z) * xb.y
         + bf2f_lo(kw.w) * xb.z + bf2f_hi(kw.w) * xb.w;
  }
  acc = wave_reduce_add(acc);
  __shared__ float red[4];
  int lane = t & 63, wid = t >> 6;
  if (lane == 0) red[wid] = acc;
  __syncthreads();
  if (t == 0) {
    float tot = red[0] + red[1] + red[2] + red[3];
    y[row] = 1.0f / tot;
  }
}

// Fused 10th matvec + loss:
// per row i: s1 = sum_j K*v_j ; s2 = sum_j K*v_j*C ; C = -EPS*log(K)
// u_i = 1/s1, so loss_i = s2/s1. atomicAdd into out.
__global__ __launch_bounds__(256) void final_kernel(
    const unsigned short* __restrict__ K, const float* __restrict__ v,
    float* __restrict__ out) {
  const int row = blockIdx.x;
  const uint4* krow = (const uint4*)(K + (size_t)row * NROWS);
  const int t = threadIdx.x;
  float s1 = 0.f, s2 = 0.f;
  #pragma unroll
  for (int s = 0; s < 4; ++s) {
    int idx = t + s * 256;
    uint4 kw = krow[idx];
    const float4* v4 = (const float4*)(v + idx * 8);
    float4 xa = v4[0];
    float4 xb = v4[1];
    float kk[8] = {bf2f_lo(kw.x), bf2f_hi(kw.x), bf2f_lo(kw.y), bf2f_hi(kw.y),
                   bf2f_lo(kw.z), bf2f_hi(kw.z), bf2f_lo(kw.w), bf2f_hi(kw.w)};
    float xv[8] = {xa.x, xa.y, xa.z, xa.w, xb.x, xb.y, xb.z, xb.w};
    #pragma unroll
    for (int e = 0; e < 8; ++e) {
      float kv = kk[e] * xv[e];
      s1 += kv;
      float c = -EPS * __logf(kk[e]);
      s2 = fmaf(kv, c, s2);
    }
  }
  s1 = wave_reduce_add(s1);
  s2 = wave_reduce_add(s2);
  __shared__ float r1[4], r2[4];
  int lane = t & 63, wid = t >> 6;
  if (lane == 0) { r1[wid] = s1; r2[wid] = s2; }
  __syncthreads();
  if (t == 0) {
    float t1 = r1[0] + r1[1] + r1[2] + r1[3];
    float t2 = r2[0] + r2[1] + r2[2] + r2[3];
    atomicAdd(out, t2 / t1);
  }
}

// ---------- launch ----------

extern "C" void kernel_launch(void* const* d_in, const int* in_sizes, int n_in,
                              void* d_out, int out_size, void* d_ws, size_t ws_size,
                              hipStream_t stream) {
  const float* P = (const float*)d_in[0];
  const float* Q = (const float*)d_in[1];
  float* out = (float*)d_out;

  char* ws = (char*)d_ws;
  unsigned short* K = (unsigned short*)ws;               // 8192*8192*2 = 134217728 B
  float* p2 = (float*)(ws + (size_t)NROWS * NROWS * 2);  // + 32 KB
  float* q2 = p2 + NROWS;
  float* ub = q2 + NROWS;
  float* vb = ub + NROWS;

  hipMemsetAsync(d_out, 0, sizeof(float), stream);

  rownorm_kernel<<<(2 * NROWS) / 4, 256, 0, stream>>>(P, Q, p2, q2);
  init_u_kernel<<<NROWS / 256, 256, 0, stream>>>(ub);
  kgen_kernel<<<dim3(NROWS / 64, NROWS / 64), 256, 0, stream>>>(P, Q, p2, q2, K);

  // 9 explicit matvecs (m=0..8): even m reads ub -> writes vb, odd reverses.
  // After m=8, vb holds v5 (the 5th v). The 10th matvec is fused into final.
  for (int m = 0; m < 9; ++m) {
    const float* xin = (m & 1) ? vb : ub;
    float* yout      = (m & 1) ? ub : vb;
    matvec_kernel<<<NROWS, 256, 0, stream>>>(K, xin, yout);
  }

  final_kernel<<<NROWS, 256, 0, stream>>>(K, vb, out);
}

// Round 2
// 408.008 us; speedup vs baseline: 1.2727x; 1.2727x over previous
//
#include <hip/hip_runtime.h>
#include <hip/hip_fp16.h>
#include <stdint.h>

#define NROWS 8192
#define DIM 64
#define EPS 0.1f

typedef float f32x4 __attribute__((ext_vector_type(4)));
typedef short s16x8 __attribute__((ext_vector_type(8)));

// ---------- helpers ----------

__device__ __forceinline__ float wave_reduce_add(float v) {
  #pragma unroll
  for (int off = 32; off > 0; off >>= 1) v += __shfl_down(v, off, 64);
  return v;
}

// float -> bf16 bits, round-to-nearest-even
__device__ __forceinline__ unsigned short f2bf(float f) {
  uint32_t u = __float_as_uint(f);
  uint32_t r = (u + 0x7fffu + ((u >> 16) & 1u)) >> 16;
  return (unsigned short)r;
}

// float in (0, 1] -> fp8 e5m2 byte (OCP). f32->f16 is HW RNE; then RNE the
// top byte of the f16 pattern (e5m2 == top 8 bits of binary16).
__device__ __forceinline__ unsigned char f2e5m2(float f) {
  unsigned short h = __half_as_ushort(__float2half(f));
  h = (unsigned short)((h + 0x7Fu + ((h >> 8) & 1u)) >> 8);
  return (unsigned char)h;
}

// e5m2 byte (already shifted: byte<<8) -> float via f16 reinterpret
__device__ __forceinline__ float e5m2f(uint32_t hbits) {
  return __half2float(__ushort_as_half((unsigned short)hbits));
}

// ---------- small kernels ----------

__global__ __launch_bounds__(256) void rownorm_kernel(
    const float* __restrict__ P, const float* __restrict__ Q,
    float* __restrict__ p2, float* __restrict__ q2) {
  int wid  = threadIdx.x >> 6;
  int lane = threadIdx.x & 63;
  int row  = blockIdx.x * 4 + wid;  // 0..16383
  const float* X;
  float* out;
  int r;
  if (row < NROWS) { X = P; out = p2; r = row; }
  else             { X = Q; out = q2; r = row - NROWS; }
  float v = X[(size_t)r * DIM + lane];
  float s = wave_reduce_add(v * v);
  if (lane == 0) out[r] = s;
}

__global__ void init_u_kernel(float* __restrict__ u) {
  int i = blockIdx.x * blockDim.x + threadIdx.x;
  if (i < NROWS) u[i] = 1.0f / 64.0f;   // u0 = ones/D, D = 64
}

// ---------- kgen: MFMA bf16, 128x128 tile per block, fp8 e5m2 output ----------
//
// LDS layout (per 128-row operand, full K=64 since D==64):
//   row stride 128 B (64 bf16), the 8 16-byte k-chunks of a row are stored at
//   position (kc ^ (row & 7)). This makes BOTH the staging ds_write_b128 and
//   the fragment ds_read_b128 conflict-free (each 16-lane phase tiles all 32
//   banks exactly 2x).

struct KgenSmem {
  unsigned char A[128 * 128];   // P tile, bf16, swizzled
  unsigned char B[128 * 128];   // Q tile, bf16, swizzled
  float p2s[128];
  float q2s[128];
};

__device__ __forceinline__ int swiz_off(int row, int kc) {
  return row * 128 + ((kc ^ (row & 7)) << 4);
}

__global__ __launch_bounds__(256) void kgen_kernel(
    const float* __restrict__ P, const float* __restrict__ Q,
    const float* __restrict__ p2, const float* __restrict__ q2,
    unsigned char* __restrict__ K) {
  __shared__ KgenSmem sm;
  const int t  = threadIdx.x;
  const int bi = blockIdx.y * 128;  // P row base (K rows)
  const int bj = blockIdx.x * 128;  // Q row base (K cols)

  // ---- stage: global fp32 -> bf16 LDS (swizzled), coalesced loads ----
  {
    const float4* P4 = (const float4*)(P + (size_t)bi * DIM);
    const float4* Q4 = (const float4*)(Q + (size_t)bj * DIM);
    #pragma unroll
    for (int it = 0; it < 4; ++it) {
      int idx = t + it * 256;      // 0..1023: row = idx>>3, kc = idx&7
      int row = idx >> 3;
      int kc  = idx & 7;
      int g   = row * 16 + kc * 2; // float4 index
      float4 a0 = P4[g], a1 = P4[g + 1];
      float4 b0 = Q4[g], b1 = Q4[g + 1];
      uint4 pa, pb;
      pa.x = f2bf(a0.x) | ((uint32_t)f2bf(a0.y) << 16);
      pa.y = f2bf(a0.z) | ((uint32_t)f2bf(a0.w) << 16);
      pa.z = f2bf(a1.x) | ((uint32_t)f2bf(a1.y) << 16);
      pa.w = f2bf(a1.z) | ((uint32_t)f2bf(a1.w) << 16);
      pb.x = f2bf(b0.x) | ((uint32_t)f2bf(b0.y) << 16);
      pb.y = f2bf(b0.z) | ((uint32_t)f2bf(b0.w) << 16);
      pb.z = f2bf(b1.x) | ((uint32_t)f2bf(b1.y) << 16);
      pb.w = f2bf(b1.z) | ((uint32_t)f2bf(b1.w) << 16);
      *(uint4*)(sm.A + swiz_off(row, kc)) = pa;
      *(uint4*)(sm.B + swiz_off(row, kc)) = pb;
    }
    if (t < 128)                   sm.p2s[t]       = p2[bi + t];
    else                           sm.q2s[t - 128] = q2[bj + t - 128];
  }
  __syncthreads();

  // ---- compute: each wave does a 64x64 subtile = 4x4 tiles of 16x16 ----
  const int w        = t >> 6;
  const int lane     = t & 63;
  const int quad     = lane >> 4;   // 0..3
  const int m16      = lane & 15;   // 0..15
  const int wave_row = (w >> 1) * 64;
  const int wave_col = (w & 1) * 64;

  f32x4 acc[4][4];
  #pragma unroll
  for (int a = 0; a < 4; ++a)
    #pragma unroll
    for (int b = 0; b < 4; ++b) acc[a][b] = (f32x4){0.f, 0.f, 0.f, 0.f};

  #pragma unroll
  for (int kstep = 0; kstep < 2; ++kstep) {
    // fragment chunk index: kc = kstep*4 + quad; 8 bf16 = k = kc*8 .. +7
    const int kc = kstep * 4 + quad;
    s16x8 af[4], bf[4];
    #pragma unroll
    for (int ti = 0; ti < 4; ++ti) {
      int arow = wave_row + ti * 16 + m16;
      af[ti] = *(const s16x8*)(sm.A + swiz_off(arow, kc));
    }
    #pragma unroll
    for (int tj = 0; tj < 4; ++tj) {
      int brow = wave_col + tj * 16 + m16;
      bf[tj] = *(const s16x8*)(sm.B + swiz_off(brow, kc));
    }
    #pragma unroll
    for (int ti = 0; ti < 4; ++ti)
      #pragma unroll
      for (int tj = 0; tj < 4; ++tj)
        acc[ti][tj] = __builtin_amdgcn_mfma_f32_16x16x32_bf16(
            af[ti], bf[tj], acc[ti][tj], 0, 0, 0);
  }

  // ---- epilogue: sq -> sqrt -> exp -> e5m2 byte store ----
  // C/D layout (verified): col = lane&15, row = quad*4 + reg
  #pragma unroll
  for (int ti = 0; ti < 4; ++ti) {
    #pragma unroll
    for (int tj = 0; tj < 4; ++tj) {
      int lcol = wave_col + tj * 16 + m16;
      int lrow0 = wave_row + ti * 16 + quad * 4;
      float qn = sm.q2s[lcol];
      #pragma unroll
      for (int r = 0; r < 4; ++r) {
        int lrow = lrow0 + r;
        float sq = sm.p2s[lrow] + qn - 2.0f * acc[ti][tj][r];
        float c  = sqrtf(fmaxf(sq, 0.0f));
        float kv = __expf(c * (-1.0f / EPS));
        K[(size_t)(bi + lrow) * NROWS + (bj + lcol)] = f2e5m2(kv);
      }
    }
  }
}

// ---------- matvec: y[i] = 1 / sum_j K[i][j]*x[j], K in fp8 e5m2 ----------

__global__ __launch_bounds__(256) void matvec_kernel(
    const unsigned char* __restrict__ K, const float* __restrict__ x,
    float* __restrict__ y) {
  const int row = blockIdx.x;
  const uint4* krow = (const uint4*)(K + (size_t)row * NROWS);  // 512 uint4
  const int t = threadIdx.x;
  float acc = 0.f;
  #pragma unroll
  for (int s = 0; s < 2; ++s) {
    int idx = t + s * 256;
    uint4 kw = krow[idx];
    const float4* x4 = (const float4*)(x + idx * 16);
    float4 x0 = x4[0], x1 = x4[1], x2 = x4[2], x3 = x4[3];
    uint32_t wd;
    wd = kw.x;
    acc += e5m2f((wd << 8) & 0xff00u)  * x0.x + e5m2f(wd & 0xff00u)         * x0.y
         + e5m2f((wd >> 8) & 0xff00u)  * x0.z + e5m2f((wd >> 16) & 0xff00u) * x0.w;
    wd = kw.y;
    acc += e5m2f((wd << 8) & 0xff00u)  * x1.x + e5m2f(wd & 0xff00u)         * x1.y
         + e5m2f((wd >> 8) & 0xff00u)  * x1.z + e5m2f((wd >> 16) & 0xff00u) * x1.w;
    wd = kw.z;
    acc += e5m2f((wd << 8) & 0xff00u)  * x2.x + e5m2f(wd & 0xff00u)         * x2.y
         + e5m2f((wd >> 8) & 0xff00u)  * x2.z + e5m2f((wd >> 16) & 0xff00u) * x2.w;
    wd = kw.w;
    acc += e5m2f((wd << 8) & 0xff00u)  * x3.x + e5m2f(wd & 0xff00u)         * x3.y
         + e5m2f((wd >> 8) & 0xff00u)  * x3.z + e5m2f((wd >> 16) & 0xff00u) * x3.w;
  }
  acc = wave_reduce_add(acc);
  __shared__ float red[4];
  int lane = t & 63, wid = t >> 6;
  if (lane == 0) red[wid] = acc;
  __syncthreads();
  if (t == 0) {
    float tot = red[0] + red[1] + red[2] + red[3];
    y[row] = 1.0f / tot;
  }
}

// ---------- fused 10th matvec + loss ----------
// per row i: s1 = sum_j K*v_j ; s2 = sum_j K*v_j*C, C = -EPS*log(K)
// u_i = 1/s1 -> row loss = s2/s1. atomicAdd into out.

__global__ __launch_bounds__(256) void final_kernel(
    const unsigned char* __restrict__ K, const float* __restrict__ v,
    float* __restrict__ out) {
  const int row = blockIdx.x;
  const uint4* krow = (const uint4*)(K + (size_t)row * NROWS);
  const int t = threadIdx.x;
  float s1 = 0.f, s2 = 0.f;
  #pragma unroll
  for (int s = 0; s < 2; ++s) {
    int idx = t + s * 256;
    uint4 kw = krow[idx];
    const float4* v4 = (const float4*)(v + idx * 16);
    float4 xv[4] = {v4[0], v4[1], v4[2], v4[3]};
    uint32_t wds[4] = {kw.x, kw.y, kw.z, kw.w};
    #pragma unroll
    for (int q = 0; q < 4; ++q) {
      uint32_t wd = wds[q];
      float kk[4] = {e5m2f((wd << 8) & 0xff00u), e5m2f(wd & 0xff00u),
                     e5m2f((wd >> 8) & 0xff00u), e5m2f((wd >> 16) & 0xff00u)};
      float xs[4] = {xv[q].x, xv[q].y, xv[q].z, xv[q].w};
      #pragma unroll
      for (int e = 0; e < 4; ++e) {
        float kv = kk[e] * xs[e];
        s1 += kv;
        float c = -EPS * __logf(fmaxf(kk[e], 1e-12f));
        s2 = fmaf(kv, c, s2);
      }
    }
  }
  s1 = wave_reduce_add(s1);
  s2 = wave_reduce_add(s2);
  __shared__ float r1[4], r2[4];
  int lane = t & 63, wid = t >> 6;
  if (lane == 0) { r1[wid] = s1; r2[wid] = s2; }
  __syncthreads();
  if (t == 0) {
    float t1 = r1[0] + r1[1] + r1[2] + r1[3];
    float t2 = r2[0] + r2[1] + r2[2] + r2[3];
    atomicAdd(out, t2 / t1);
  }
}

// ---------- launch ----------

extern "C" void kernel_launch(void* const* d_in, const int* in_sizes, int n_in,
                              void* d_out, int out_size, void* d_ws, size_t ws_size,
                              hipStream_t stream) {
  const float* P = (const float*)d_in[0];
  const float* Q = (const float*)d_in[1];
  float* out = (float*)d_out;

  char* ws = (char*)d_ws;
  unsigned char* K = (unsigned char*)ws;                 // 8192*8192 = 67108864 B
  float* p2 = (float*)(ws + (size_t)NROWS * NROWS);
  float* q2 = p2 + NROWS;
  float* ub = q2 + NROWS;
  float* vb = ub + NROWS;

  hipMemsetAsync(d_out, 0, sizeof(float), stream);

  rownorm_kernel<<<(2 * NROWS) / 4, 256, 0, stream>>>(P, Q, p2, q2);
  init_u_kernel<<<NROWS / 256, 256, 0, stream>>>(ub);
  kgen_kernel<<<dim3(NROWS / 128, NROWS / 128), 256, 0, stream>>>(P, Q, p2, q2, K);

  // 9 explicit matvecs; the 10th is fused into final_kernel.
  for (int m = 0; m < 9; ++m) {
    const float* xin = (m & 1) ? vb : ub;
    float* yout      = (m & 1) ? ub : vb;
    matvec_kernel<<<NROWS, 256, 0, stream>>>(K, xin, yout);
  }

  final_kernel<<<NROWS, 256, 0, stream>>>(K, vb, out);
}

// Round 3
// 332.988 us; speedup vs baseline: 1.5594x; 1.2253x over previous
//
#include <hip/hip_runtime.h>
#include <hip/hip_fp16.h>
#include <stdint.h>

#define NROWS 8192
#define DIM 64
#define EPS 0.1f

typedef float f32x4 __attribute__((ext_vector_type(4)));
typedef short s16x8 __attribute__((ext_vector_type(8)));

// ---------- helpers ----------

__device__ __forceinline__ float wave_reduce_add(float v) {
  #pragma unroll
  for (int off = 32; off > 0; off >>= 1) v += __shfl_down(v, off, 64);
  return v;
}

// float -> bf16 bits, round-to-nearest-even
__device__ __forceinline__ unsigned short f2bf(float f) {
  uint32_t u = __float_as_uint(f);
  uint32_t r = (u + 0x7fffu + ((u >> 16) & 1u)) >> 16;
  return (unsigned short)r;
}

// float in (0, 1] -> fp8 e5m2 byte (OCP). f32->f16 is HW RNE; then RNE the
// top byte of the f16 pattern (e5m2 == top 8 bits of binary16).
__device__ __forceinline__ unsigned char f2e5m2(float f) {
  unsigned short h = __half_as_ushort(__float2half(f));
  h = (unsigned short)((h + 0x7Fu + ((h >> 8) & 1u)) >> 8);
  return (unsigned char)h;
}

// e5m2 byte (already shifted: byte<<8) -> float via f16 reinterpret
__device__ __forceinline__ float e5m2f(uint32_t hbits) {
  return __half2float(__ushort_as_half((unsigned short)hbits));
}

// ---------- small kernels ----------

__global__ __launch_bounds__(256) void rownorm_kernel(
    const float* __restrict__ P, const float* __restrict__ Q,
    float* __restrict__ p2, float* __restrict__ q2) {
  int wid  = threadIdx.x >> 6;
  int lane = threadIdx.x & 63;
  int row  = blockIdx.x * 4 + wid;  // 0..16383
  const float* X;
  float* out;
  int r;
  if (row < NROWS) { X = P; out = p2; r = row; }
  else             { X = Q; out = q2; r = row - NROWS; }
  float v = X[(size_t)r * DIM + lane];
  float s = wave_reduce_add(v * v);
  if (lane == 0) out[r] = s;
}

__global__ void init_u_kernel(float* __restrict__ u) {
  int i = blockIdx.x * blockDim.x + threadIdx.x;
  if (i < NROWS) u[i] = 1.0f / 64.0f;   // u0 = ones/D, D = 64
}

// ---------- kgen: MFMA bf16, 128x128 tile per block, fp8 e5m2 output ----------

struct KgenSmem {
  unsigned char A[128 * 128];   // P tile, bf16, swizzled
  unsigned char B[128 * 128];   // Q tile, bf16, swizzled
  float p2s[128];
  float q2s[128];
};

__device__ __forceinline__ int swiz_off(int row, int kc) {
  return row * 128 + ((kc ^ (row & 7)) << 4);
}

__global__ __launch_bounds__(256) void kgen_kernel(
    const float* __restrict__ P, const float* __restrict__ Q,
    const float* __restrict__ p2, const float* __restrict__ q2,
    unsigned char* __restrict__ K) {
  __shared__ KgenSmem sm;
  const int t  = threadIdx.x;
  const int bi = blockIdx.y * 128;  // P row base (K rows)
  const int bj = blockIdx.x * 128;  // Q row base (K cols)

  // ---- stage: global fp32 -> bf16 LDS (swizzled), coalesced loads ----
  {
    const float4* P4 = (const float4*)(P + (size_t)bi * DIM);
    const float4* Q4 = (const float4*)(Q + (size_t)bj * DIM);
    #pragma unroll
    for (int it = 0; it < 4; ++it) {
      int idx = t + it * 256;      // 0..1023: row = idx>>3, kc = idx&7
      int row = idx >> 3;
      int kc  = idx & 7;
      int g   = row * 16 + kc * 2; // float4 index
      float4 a0 = P4[g], a1 = P4[g + 1];
      float4 b0 = Q4[g], b1 = Q4[g + 1];
      uint4 pa, pb;
      pa.x = f2bf(a0.x) | ((uint32_t)f2bf(a0.y) << 16);
      pa.y = f2bf(a0.z) | ((uint32_t)f2bf(a0.w) << 16);
      pa.z = f2bf(a1.x) | ((uint32_t)f2bf(a1.y) << 16);
      pa.w = f2bf(a1.z) | ((uint32_t)f2bf(a1.w) << 16);
      pb.x = f2bf(b0.x) | ((uint32_t)f2bf(b0.y) << 16);
      pb.y = f2bf(b0.z) | ((uint32_t)f2bf(b0.w) << 16);
      pb.z = f2bf(b1.x) | ((uint32_t)f2bf(b1.y) << 16);
      pb.w = f2bf(b1.z) | ((uint32_t)f2bf(b1.w) << 16);
      *(uint4*)(sm.A + swiz_off(row, kc)) = pa;
      *(uint4*)(sm.B + swiz_off(row, kc)) = pb;
    }
    if (t < 128)                   sm.p2s[t]       = p2[bi + t];
    else                           sm.q2s[t - 128] = q2[bj + t - 128];
  }
  __syncthreads();

  // ---- compute: each wave does a 64x64 subtile = 4x4 tiles of 16x16 ----
  const int w        = t >> 6;
  const int lane     = t & 63;
  const int quad     = lane >> 4;   // 0..3
  const int m16      = lane & 15;   // 0..15
  const int wave_row = (w >> 1) * 64;
  const int wave_col = (w & 1) * 64;

  f32x4 acc[4][4];
  #pragma unroll
  for (int a = 0; a < 4; ++a)
    #pragma unroll
    for (int b = 0; b < 4; ++b) acc[a][b] = (f32x4){0.f, 0.f, 0.f, 0.f};

  #pragma unroll
  for (int kstep = 0; kstep < 2; ++kstep) {
    const int kc = kstep * 4 + quad;
    s16x8 af[4], bf[4];
    #pragma unroll
    for (int ti = 0; ti < 4; ++ti) {
      int arow = wave_row + ti * 16 + m16;
      af[ti] = *(const s16x8*)(sm.A + swiz_off(arow, kc));
    }
    #pragma unroll
    for (int tj = 0; tj < 4; ++tj) {
      int brow = wave_col + tj * 16 + m16;
      bf[tj] = *(const s16x8*)(sm.B + swiz_off(brow, kc));
    }
    #pragma unroll
    for (int ti = 0; ti < 4; ++ti)
      #pragma unroll
      for (int tj = 0; tj < 4; ++tj)
        acc[ti][tj] = __builtin_amdgcn_mfma_f32_16x16x32_bf16(
            af[ti], bf[tj], acc[ti][tj], 0, 0, 0);
  }

  // ---- epilogue: sq -> sqrt -> exp -> e5m2 byte store ----
  // C/D layout (verified): col = lane&15, row = quad*4 + reg
  #pragma unroll
  for (int ti = 0; ti < 4; ++ti) {
    #pragma unroll
    for (int tj = 0; tj < 4; ++tj) {
      int lcol = wave_col + tj * 16 + m16;
      int lrow0 = wave_row + ti * 16 + quad * 4;
      float qn = sm.q2s[lcol];
      #pragma unroll
      for (int r = 0; r < 4; ++r) {
        int lrow = lrow0 + r;
        float sq = sm.p2s[lrow] + qn - 2.0f * acc[ti][tj][r];
        float c  = sqrtf(fmaxf(sq, 0.0f));
        float kv = __expf(c * (-1.0f / EPS));
        K[(size_t)(bi + lrow) * NROWS + (bj + lcol)] = f2e5m2(kv);
      }
    }
  }
}

// ---------- matvec: y[i] = 1 / sum_j K[i][j]*x[j], K in fp8 e5m2 ----------

__global__ __launch_bounds__(256) void matvec_kernel(
    const unsigned char* __restrict__ K, const float* __restrict__ x,
    float* __restrict__ y) {
  const int row = blockIdx.x;
  const uint4* krow = (const uint4*)(K + (size_t)row * NROWS);  // 512 uint4
  const int t = threadIdx.x;
  float acc = 0.f;
  #pragma unroll
  for (int s = 0; s < 2; ++s) {
    int idx = t + s * 256;
    uint4 kw = krow[idx];
    const float4* x4 = (const float4*)(x + idx * 16);
    float4 x0 = x4[0], x1 = x4[1], x2 = x4[2], x3 = x4[3];
    uint32_t wd;
    wd = kw.x;
    acc += e5m2f((wd << 8) & 0xff00u)  * x0.x + e5m2f(wd & 0xff00u)         * x0.y
         + e5m2f((wd >> 8) & 0xff00u)  * x0.z + e5m2f((wd >> 16) & 0xff00u) * x0.w;
    wd = kw.y;
    acc += e5m2f((wd << 8) & 0xff00u)  * x1.x + e5m2f(wd & 0xff00u)         * x1.y
         + e5m2f((wd >> 8) & 0xff00u)  * x1.z + e5m2f((wd >> 16) & 0xff00u) * x1.w;
    wd = kw.z;
    acc += e5m2f((wd << 8) & 0xff00u)  * x2.x + e5m2f(wd & 0xff00u)         * x2.y
         + e5m2f((wd >> 8) & 0xff00u)  * x2.z + e5m2f((wd >> 16) & 0xff00u) * x2.w;
    wd = kw.w;
    acc += e5m2f((wd << 8) & 0xff00u)  * x3.x + e5m2f(wd & 0xff00u)         * x3.y
         + e5m2f((wd >> 8) & 0xff00u)  * x3.z + e5m2f((wd >> 16) & 0xff00u) * x3.w;
  }
  acc = wave_reduce_add(acc);
  __shared__ float red[4];
  int lane = t & 63, wid = t >> 6;
  if (lane == 0) red[wid] = acc;
  __syncthreads();
  if (t == 0) {
    float tot = red[0] + red[1] + red[2] + red[3];
    y[row] = 1.0f / tot;
  }
}

// ---------- fused 10th matvec + loss (per-row partial, NO atomics) ----------
// per row i: s1 = sum_j K*v_j ; s2 = sum_j K*v_j*C, C = -EPS*log(K)
// u_i = 1/s1 -> row loss = s2/s1 -> partials[i]. Reduced by reduce_kernel.

__global__ __launch_bounds__(256) void final_kernel(
    const unsigned char* __restrict__ K, const float* __restrict__ v,
    float* __restrict__ partials) {
  const int row = blockIdx.x;
  const uint4* krow = (const uint4*)(K + (size_t)row * NROWS);
  const int t = threadIdx.x;
  float s1 = 0.f, s2 = 0.f;
  #pragma unroll
  for (int s = 0; s < 2; ++s) {
    int idx = t + s * 256;
    uint4 kw = krow[idx];
    const float4* v4 = (const float4*)(v + idx * 16);
    float4 xv[4] = {v4[0], v4[1], v4[2], v4[3]};
    uint32_t wds[4] = {kw.x, kw.y, kw.z, kw.w};
    #pragma unroll
    for (int q = 0; q < 4; ++q) {
      uint32_t wd = wds[q];
      float kk[4] = {e5m2f((wd << 8) & 0xff00u), e5m2f(wd & 0xff00u),
                     e5m2f((wd >> 8) & 0xff00u), e5m2f((wd >> 16) & 0xff00u)};
      float xs[4] = {xv[q].x, xv[q].y, xv[q].z, xv[q].w};
      #pragma unroll
      for (int e = 0; e < 4; ++e) {
        float kv = kk[e] * xs[e];
        s1 += kv;
        float c = -EPS * __logf(fmaxf(kk[e], 1e-12f));
        s2 = fmaf(kv, c, s2);
      }
    }
  }
  s1 = wave_reduce_add(s1);
  s2 = wave_reduce_add(s2);
  __shared__ float r1[4], r2[4];
  int lane = t & 63, wid = t >> 6;
  if (lane == 0) { r1[wid] = s1; r2[wid] = s2; }
  __syncthreads();
  if (t == 0) {
    float t1 = r1[0] + r1[1] + r1[2] + r1[3];
    float t2 = r2[0] + r2[1] + r2[2] + r2[3];
    partials[row] = t2 / t1;
  }
}

// Sum 8192 partials -> out[0]. One block of 256 threads, coalesced reads.
__global__ __launch_bounds__(256) void reduce_kernel(
    const float* __restrict__ partials, float* __restrict__ out) {
  const int t = threadIdx.x;
  float s = 0.f;
  #pragma unroll
  for (int i = 0; i < NROWS / 256; ++i) s += partials[t + i * 256];
  s = wave_reduce_add(s);
  __shared__ float red[4];
  int lane = t & 63, wid = t >> 6;
  if (lane == 0) red[wid] = s;
  __syncthreads();
  if (t == 0) out[0] = red[0] + red[1] + red[2] + red[3];
}

// ---------- launch ----------

extern "C" void kernel_launch(void* const* d_in, const int* in_sizes, int n_in,
                              void* d_out, int out_size, void* d_ws, size_t ws_size,
                              hipStream_t stream) {
  const float* P = (const float*)d_in[0];
  const float* Q = (const float*)d_in[1];
  float* out = (float*)d_out;

  char* ws = (char*)d_ws;
  unsigned char* K = (unsigned char*)ws;                 // 8192*8192 = 67108864 B
  float* p2 = (float*)(ws + (size_t)NROWS * NROWS);
  float* q2 = p2 + NROWS;
  float* ub = q2 + NROWS;
  float* vb = ub + NROWS;
  float* partials = vb + NROWS;                          // 8192 floats

  rownorm_kernel<<<(2 * NROWS) / 4, 256, 0, stream>>>(P, Q, p2, q2);
  init_u_kernel<<<NROWS / 256, 256, 0, stream>>>(ub);
  kgen_kernel<<<dim3(NROWS / 128, NROWS / 128), 256, 0, stream>>>(P, Q, p2, q2, K);

  // 9 explicit matvecs; the 10th is fused into final_kernel.
  for (int m = 0; m < 9; ++m) {
    const float* xin = (m & 1) ? vb : ub;
    float* yout      = (m & 1) ? ub : vb;
    matvec_kernel<<<NROWS, 256, 0, stream>>>(K, xin, yout);
  }

  final_kernel<<<NROWS, 256, 0, stream>>>(K, vb, partials);
  reduce_kernel<<<1, 256, 0, stream>>>(partials, out);
}